// Round 1
// baseline (492.148 us; speedup 1.0000x reference)
//
#include <hip/hip_runtime.h>
#include <cstdint>
#include <cstddef>

#define BB 16
#define CC 512
#define NN 4096

typedef __attribute__((ext_vector_type(4))) float f32x4;
typedef __attribute__((ext_vector_type(8))) short bf16x8;

__device__ __forceinline__ unsigned short f2bf(float f) {
  unsigned int u = __float_as_uint(f);
  u += 0x7FFFu + ((u >> 16) & 1u);   // round-to-nearest-even
  return (unsigned short)(u >> 16);
}
__device__ __forceinline__ float bf2f(unsigned short h) {
  return __uint_as_float(((unsigned int)h) << 16);
}

// async global->LDS, 16B per lane. LDS dest must be wave-uniform base; HW adds lane*16.
__device__ __forceinline__ void gload16(const unsigned short* g, short* l) {
  __builtin_amdgcn_global_load_lds(
      (const __attribute__((address_space(1))) unsigned int*)g,
      (__attribute__((address_space(3))) unsigned int*)(__attribute__((address_space(3))) short*)l,
      16, 0, 0);
}

// ---------------- Kernel A: x -> bf16 hi/lo, transposed hi, row partial sums ----------
__global__ __launch_bounds__(256) void k_convert(
    const float* __restrict__ x,
    unsigned short* __restrict__ qhi,
    unsigned short* __restrict__ qlo,
    unsigned short* __restrict__ qt,
    float* __restrict__ part)
{
  const int nt = blockIdx.x;     // 16 tiles of 256 n
  const int ct = blockIdx.y;     // 8 tiles of 64 c
  const int b  = blockIdx.z;
  const int c0 = ct << 6;
  const int n0 = nt << 8;
  const int t  = threadIdx.x;
  const int w  = t >> 6;
  const int l  = t & 63;

  __shared__ unsigned short lt[256 * 65];   // [n_local][c_local], pitch 65 (bank spread)
  __shared__ float rsum[64];

  const size_t xb = (size_t)b * CC * NN;

  for (int i = 0; i < 16; ++i) {
    const int r = (i << 2) + w;                       // c row in tile (wave-uniform)
    const size_t off = xb + (size_t)(c0 + r) * NN + n0 + (l << 2);
    const float4 v = *(const float4*)(x + off);
    const unsigned short h0 = f2bf(v.x), h1 = f2bf(v.y), h2 = f2bf(v.z), h3 = f2bf(v.w);
    const unsigned short g0 = f2bf(v.x - bf2f(h0)), g1 = f2bf(v.y - bf2f(h1)),
                         g2 = f2bf(v.z - bf2f(h2)), g3 = f2bf(v.w - bf2f(h3));
    *(ushort4*)(qhi + off) = make_ushort4(h0, h1, h2, h3);
    *(ushort4*)(qlo + off) = make_ushort4(g0, g1, g2, g3);
    const int nl = l << 2;
    lt[(nl + 0) * 65 + r] = h0;
    lt[(nl + 1) * 65 + r] = h1;
    lt[(nl + 2) * 65 + r] = h2;
    lt[(nl + 3) * 65 + r] = h3;
    float s = v.x + v.y + v.z + v.w;
    #pragma unroll
    for (int o = 32; o > 0; o >>= 1) s += __shfl_down(s, o);
    if (l == 0) rsum[r] = s;                          // each wave owns distinct rows
  }
  __syncthreads();
  if (t < 64) part[((size_t)b * CC + c0 + t) * 16 + nt] = rsum[t];

  // transposed write: qt[b][n][c]
  #pragma unroll
  for (int p = 0; p < 8; ++p) {
    const int n   = (p << 5) + (t >> 3);
    const int cc8 = (t & 7) << 3;
    const unsigned short* e = &lt[n * 65 + cc8];
    uint4 pk;
    pk.x = (unsigned)e[0] | ((unsigned)e[1] << 16);
    pk.y = (unsigned)e[2] | ((unsigned)e[3] << 16);
    pk.z = (unsigned)e[4] | ((unsigned)e[5] << 16);
    pk.w = (unsigned)e[6] | ((unsigned)e[7] << 16);
    *(uint4*)(qt + ((size_t)b * NN + n0 + n) * CC + c0 + cc8) = pk;
  }
}

// ---------------- Kernel A2: sum row partials -> pooled_x raw sums --------------------
__global__ __launch_bounds__(256) void k_sumpart(const float* __restrict__ part,
                                                 float* __restrict__ px)
{
  const int g = blockIdx.x * 256 + threadIdx.x;   // 0..8191 = b*512+c
  float s = 0.f;
  #pragma unroll
  for (int i = 0; i < 16; ++i) s += part[(size_t)g * 16 + i];
  px[g] = s;
}

// ---------------- Kernel B: energy = HH + HL + LH (split-precision bf16 MFMA) ---------
// 128x128 tile per block, 4 waves (64x64/wave), BK=32, double-buffered gload_lds.
__global__ __launch_bounds__(256, 1) void k_energy(
    const unsigned short* __restrict__ qhi,
    const unsigned short* __restrict__ qlo,
    float* __restrict__ E)
{
  const int bx = blockIdx.x;                // 256 blocks
  const int b = bx >> 4, tr = (bx >> 2) & 3, tc = bx & 3;
  const int t = threadIdx.x, w = t >> 6, l = t & 63;
  const int wr = w >> 1, wc = w & 1;

  __shared__ short lds[2][4][128 * 32];     // [buf][Ahi,Alo,Bhi,Blo]  = 64 KiB

  const size_t qoff = (size_t)b * CC * NN;
  const unsigned short* sAh = qhi + qoff + (size_t)(tr * 128) * NN;
  const unsigned short* sAl = qlo + qoff + (size_t)(tr * 128) * NN;
  const unsigned short* sBh = qhi + qoff + (size_t)(tc * 128) * NN;
  const unsigned short* sBl = qlo + qoff + (size_t)(tc * 128) * NN;

  // staging: chunk = w*64+l (and +256); row = chunk>>2; stored kchunk = chunk&3;
  // logical kchunk = stored ^ ((row>>2)&3)  (XOR swizzle, rule #21: pre-swizzled source)
  const int r1 = w * 16 + (l >> 2);
  const int kl = (((l & 3) ^ (l >> 4)) << 3);          // logical k elem offset
  const int d1 = w * 512;                               // LDS short offset (wave-uniform)
  const int d2 = 2048 + w * 512;

  // fragment read: row = base + (l&15); logical chunk = l>>4; stored = logical ^ ((row>>2)&3)
  const int laneoff = ((l & 15) << 5) + ((((l >> 4) ^ ((l >> 2) & 3))) << 3);

  f32x4 acc1[4][4] = {}; f32x4 acc2[4][4] = {}; f32x4 acc3[4][4] = {};

  auto stage = [&](int buf, int kk) {
    const int k0 = kk * 32 + kl;
    gload16(sAh + (size_t)r1 * NN + k0,        &lds[buf][0][d1]);
    gload16(sAh + (size_t)(r1 + 64) * NN + k0, &lds[buf][0][d2]);
    gload16(sAl + (size_t)r1 * NN + k0,        &lds[buf][1][d1]);
    gload16(sAl + (size_t)(r1 + 64) * NN + k0, &lds[buf][1][d2]);
    gload16(sBh + (size_t)r1 * NN + k0,        &lds[buf][2][d1]);
    gload16(sBh + (size_t)(r1 + 64) * NN + k0, &lds[buf][2][d2]);
    gload16(sBl + (size_t)r1 * NN + k0,        &lds[buf][3][d1]);
    gload16(sBl + (size_t)(r1 + 64) * NN + k0, &lds[buf][3][d2]);
  };

  stage(0, 0);
  __syncthreads();

  for (int kk = 0; kk < 128; ++kk) {
    const int cur = kk & 1;
    if (kk + 1 < 128) stage(cur ^ 1, kk + 1);
    const short* Ah = &lds[cur][0][0];
    const short* Al = &lds[cur][1][0];
    const short* Bh = &lds[cur][2][0];
    const short* Bl = &lds[cur][3][0];
    bf16x8 ah[4], al[4], bh[4], bl[4];
    #pragma unroll
    for (int m = 0; m < 4; ++m) {
      const int off = (wr * 64 + m * 16) * 32 + laneoff;
      ah[m] = *(const bf16x8*)(Ah + off);
      al[m] = *(const bf16x8*)(Al + off);
    }
    #pragma unroll
    for (int n = 0; n < 4; ++n) {
      const int off = (wc * 64 + n * 16) * 32 + laneoff;
      bh[n] = *(const bf16x8*)(Bh + off);
      bl[n] = *(const bf16x8*)(Bl + off);
    }
    #pragma unroll
    for (int m = 0; m < 4; ++m)
      #pragma unroll
      for (int n = 0; n < 4; ++n) {
        acc1[m][n] = __builtin_amdgcn_mfma_f32_16x16x32_bf16(ah[m], bh[n], acc1[m][n], 0, 0, 0);
        acc2[m][n] = __builtin_amdgcn_mfma_f32_16x16x32_bf16(ah[m], bl[n], acc2[m][n], 0, 0, 0);
        acc3[m][n] = __builtin_amdgcn_mfma_f32_16x16x32_bf16(al[m], bh[n], acc3[m][n], 0, 0, 0);
      }
    __syncthreads();
  }

  const int row0 = tr * 128 + wr * 64, col0 = tc * 128 + wc * 64;
  float* Eb = E + (size_t)b * CC * CC;
  #pragma unroll
  for (int m = 0; m < 4; ++m)
    #pragma unroll
    for (int n = 0; n < 4; ++n)
      #pragma unroll
      for (int r = 0; r < 4; ++r) {
        const int row = row0 + m * 16 + ((l >> 4) << 2) + r;   // C/D: row=(lane>>4)*4+reg
        const int col = col0 + n * 16 + (l & 15);              //      col=lane&15
        Eb[(size_t)row * CC + col] = acc1[m][n][r] + acc2[m][n][r] + acc3[m][n][r];
      }
}

// ---------------- Kernel C: att = softmax(-E) per row; pooled_out = att . mean_x ------
__global__ __launch_bounds__(64) void k_softmax(
    const float* __restrict__ E, const float* __restrict__ px,
    unsigned short* __restrict__ att, float* __restrict__ po)
{
  const int bx = blockIdx.x;                  // 8192 = b*512+c
  const int b = bx >> 9, c = bx & 511;
  const int l = threadIdx.x;
  const float* row = E + ((size_t)b * CC + c) * CC;
  float v[8];
  float mn = 1e30f;
  #pragma unroll
  for (int i = 0; i < 8; ++i) { v[i] = row[l + i * 64]; mn = fminf(mn, v[i]); }
  #pragma unroll
  for (int o = 32; o > 0; o >>= 1) mn = fminf(mn, __shfl_xor(mn, o));
  float s = 0.f;
  #pragma unroll
  for (int i = 0; i < 8; ++i) { v[i] = __expf(mn - v[i]); s += v[i]; }
  float dot = 0.f;
  const float* pxb = px + (size_t)b * CC;
  #pragma unroll
  for (int i = 0; i < 8; ++i) dot += v[i] * pxb[l + i * 64];
  #pragma unroll
  for (int o = 32; o > 0; o >>= 1) { s += __shfl_xor(s, o); dot += __shfl_xor(dot, o); }
  const float inv = 1.f / s;
  unsigned short* arow = att + ((size_t)b * CC + c) * CC;
  #pragma unroll
  for (int i = 0; i < 8; ++i) arow[l + i * 64] = f2bf(v[i] * inv);
  if (l == 0) po[(size_t)b * CC + c] = dot / (s * 4096.f);
}

// ---------------- Kernel D: SE MLP -> se[b][c] -----------------------------------------
__global__ __launch_bounds__(256) void k_mlp(
    const float* __restrict__ px, const float* __restrict__ po,
    const float* __restrict__ w1, const float* __restrict__ b1,
    const float* __restrict__ w2, const float* __restrict__ b2,
    float* __restrict__ se)
{
  const int b = blockIdx.x, t = threadIdx.x;
  __shared__ float p[1024];
  __shared__ float hp[64][5];
  __shared__ float h[64];
  for (int i = t; i < 1024; i += 256)
    p[i] = (i < 512) ? px[(size_t)b * 512 + i] * (1.f / 4096.f)
                     : po[(size_t)b * 512 + i - 512];
  __syncthreads();
  {
    const int j = t >> 2, q = t & 3;
    float s = 0.f;
    const float* wr = w1 + (size_t)j * 1024 + q * 256;
    const float* pp = p + q * 256;
    for (int k = 0; k < 256; ++k) s += pp[k] * wr[k];
    hp[j][q] = s;
  }
  __syncthreads();
  if (t < 64) h[t] = fmaxf(hp[t][0] + hp[t][1] + hp[t][2] + hp[t][3] + b1[t], 0.f);
  __syncthreads();
  for (int c = t; c < 512; c += 256) {
    float s = b2[c];
    for (int j = 0; j < 64; ++j) s += h[j] * w2[(size_t)c * 64 + j];
    se[(size_t)b * 512 + c] = 1.f / (1.f + __expf(-s));
  }
}

// ---------------- Kernel E: out = att @ q, fused blend se*x + (1-se)*out --------------
__global__ __launch_bounds__(256) void k_out(
    const unsigned short* __restrict__ att,
    const unsigned short* __restrict__ qt,
    const float* __restrict__ se,
    const float* __restrict__ x,
    float* __restrict__ out)
{
  const int bx = blockIdx.x;                      // 2048 blocks
  const int b = bx >> 7, tt = bx & 127, tr = tt >> 5, tc = tt & 31;
  const int t = threadIdx.x, w = t >> 6, l = t & 63;
  const int wr = w >> 1, wc = w & 1;

  __shared__ short lds[2][2][128 * 32];           // 32 KiB

  const unsigned short* sA = att + (size_t)b * CC * CC + (size_t)(tr * 128) * CC;
  const unsigned short* sB = qt  + (size_t)b * NN * CC + (size_t)(tc * 128) * CC;

  const int r1 = w * 16 + (l >> 2);
  const int kl = (((l & 3) ^ (l >> 4)) << 3);
  const int d1 = w * 512, d2 = 2048 + w * 512;
  const int laneoff = ((l & 15) << 5) + ((((l >> 4) ^ ((l >> 2) & 3))) << 3);

  f32x4 acc[4][4] = {};

  auto stage = [&](int buf, int kk) {
    const int k0 = kk * 32 + kl;
    gload16(sA + (size_t)r1 * CC + k0,        &lds[buf][0][d1]);
    gload16(sA + (size_t)(r1 + 64) * CC + k0, &lds[buf][0][d2]);
    gload16(sB + (size_t)r1 * CC + k0,        &lds[buf][1][d1]);
    gload16(sB + (size_t)(r1 + 64) * CC + k0, &lds[buf][1][d2]);
  };

  stage(0, 0);
  __syncthreads();

  for (int kk = 0; kk < 16; ++kk) {
    const int cur = kk & 1;
    if (kk + 1 < 16) stage(cur ^ 1, kk + 1);
    const short* A  = &lds[cur][0][0];
    const short* Bm = &lds[cur][1][0];
    bf16x8 af[4], bf[4];
    #pragma unroll
    for (int m = 0; m < 4; ++m) af[m] = *(const bf16x8*)(A  + (wr * 64 + m * 16) * 32 + laneoff);
    #pragma unroll
    for (int n = 0; n < 4; ++n) bf[n] = *(const bf16x8*)(Bm + (wc * 64 + n * 16) * 32 + laneoff);
    #pragma unroll
    for (int m = 0; m < 4; ++m)
      #pragma unroll
      for (int n = 0; n < 4; ++n)
        acc[m][n] = __builtin_amdgcn_mfma_f32_16x16x32_bf16(af[m], bf[n], acc[m][n], 0, 0, 0);
    __syncthreads();
  }

  const int row0 = tr * 128 + wr * 64, col0 = tc * 128 + wc * 64;
  const size_t xb = (size_t)b * CC * NN;
  #pragma unroll
  for (int m = 0; m < 4; ++m)
    #pragma unroll
    for (int r = 0; r < 4; ++r) {
      const int c = row0 + m * 16 + ((l >> 4) << 2) + r;
      const float sv = se[(size_t)b * CC + c];
      const float om = 1.f - sv;
      const size_t ro = xb + (size_t)c * NN;
      #pragma unroll
      for (int n = 0; n < 4; ++n) {
        const int ng = col0 + n * 16 + (l & 15);
        out[ro + ng] = sv * x[ro + ng] + om * acc[m][n][r];
      }
    }
}

// ---------------------------------------------------------------------------------------
extern "C" void kernel_launch(void* const* d_in, const int* in_sizes, int n_in,
                              void* d_out, int out_size, void* d_ws, size_t ws_size,
                              hipStream_t stream) {
  (void)in_sizes; (void)n_in; (void)out_size;
  const float* x  = (const float*)d_in[0];
  const float* w1 = (const float*)d_in[1];
  const float* b1 = (const float*)d_in[2];
  const float* w2 = (const float*)d_in[3];
  const float* b2 = (const float*)d_in[4];
  float* out = (float*)d_out;

  if (ws_size < 227115008ull) return;   // fail loudly (output stays poisoned)

  char* ws = (char*)d_ws;
  unsigned short* qhi = (unsigned short*)(ws);
  unsigned short* qlo = (unsigned short*)(ws + 67108864);
  unsigned short* qt  = (unsigned short*)(ws + 134217728);
  float*          E   = (float*)(ws + 201326592);
  unsigned short* att = (unsigned short*)(ws + 218103808);
  float*          part= (float*)(ws + 226492416);
  float*          px  = (float*)(ws + 227016704);
  float*          po  = (float*)(ws + 227049472);
  float*          se  = (float*)(ws + 227082240);

  k_convert<<<dim3(16, 8, 16), 256, 0, stream>>>(x, qhi, qlo, qt, part);
  k_sumpart<<<32, 256, 0, stream>>>(part, px);
  k_energy<<<256, 256, 0, stream>>>(qhi, qlo, E);
  k_softmax<<<8192, 64, 0, stream>>>(E, px, att, po);
  k_mlp<<<16, 256, 0, stream>>>(px, po, w1, b1, w2, b2, se);
  k_out<<<2048, 256, 0, stream>>>(att, qt, se, x, out);
}

// Round 2
// 336.886 us; speedup vs baseline: 1.4609x; 1.4609x over previous
//
#include <hip/hip_runtime.h>
#include <cstdint>
#include <cstddef>

#define BB 16
#define CC 512
#define NN 4096

typedef __attribute__((ext_vector_type(4))) float f32x4;
typedef __attribute__((ext_vector_type(8))) short bf16x8;

__device__ __forceinline__ unsigned short f2bf(float f) {
  unsigned int u = __float_as_uint(f);
  u += 0x7FFFu + ((u >> 16) & 1u);   // round-to-nearest-even
  return (unsigned short)(u >> 16);
}
__device__ __forceinline__ float bf2f(unsigned short h) {
  return __uint_as_float(((unsigned int)h) << 16);
}

// async global->LDS, 16B per lane. LDS dest must be wave-uniform base; HW adds lane*16.
__device__ __forceinline__ void gload16(const unsigned short* g, short* l) {
  __builtin_amdgcn_global_load_lds(
      (const __attribute__((address_space(1))) unsigned int*)g,
      (__attribute__((address_space(3))) unsigned int*)(__attribute__((address_space(3))) short*)l,
      16, 0, 0);
}

// ---------------- Kernel A: x -> bf16 hi/lo, transposed hi, row partial sums ----------
__global__ __launch_bounds__(256) void k_convert(
    const float* __restrict__ x,
    unsigned short* __restrict__ qhi,
    unsigned short* __restrict__ qlo,
    unsigned short* __restrict__ qt,
    float* __restrict__ part)
{
  const int nt = blockIdx.x;     // 16 tiles of 256 n
  const int ct = blockIdx.y;     // 8 tiles of 64 c
  const int b  = blockIdx.z;
  const int c0 = ct << 6;
  const int n0 = nt << 8;
  const int t  = threadIdx.x;
  const int w  = t >> 6;
  const int l  = t & 63;

  __shared__ unsigned short lt[256 * 65];   // [n_local][c_local], pitch 65 (bank spread)
  __shared__ float rsum[64];

  const size_t xb = (size_t)b * CC * NN;

  for (int i = 0; i < 16; ++i) {
    const int r = (i << 2) + w;                       // c row in tile (wave-uniform)
    const size_t off = xb + (size_t)(c0 + r) * NN + n0 + (l << 2);
    const float4 v = *(const float4*)(x + off);
    const unsigned short h0 = f2bf(v.x), h1 = f2bf(v.y), h2 = f2bf(v.z), h3 = f2bf(v.w);
    const unsigned short g0 = f2bf(v.x - bf2f(h0)), g1 = f2bf(v.y - bf2f(h1)),
                         g2 = f2bf(v.z - bf2f(h2)), g3 = f2bf(v.w - bf2f(h3));
    *(ushort4*)(qhi + off) = make_ushort4(h0, h1, h2, h3);
    *(ushort4*)(qlo + off) = make_ushort4(g0, g1, g2, g3);
    const int nl = l << 2;
    lt[(nl + 0) * 65 + r] = h0;
    lt[(nl + 1) * 65 + r] = h1;
    lt[(nl + 2) * 65 + r] = h2;
    lt[(nl + 3) * 65 + r] = h3;
    float s = v.x + v.y + v.z + v.w;
    #pragma unroll
    for (int o = 32; o > 0; o >>= 1) s += __shfl_down(s, o);
    if (l == 0) rsum[r] = s;                          // each wave owns distinct rows
  }
  __syncthreads();
  if (t < 64) part[((size_t)b * CC + c0 + t) * 16 + nt] = rsum[t];

  // transposed write: qt[b][n][c]
  #pragma unroll
  for (int p = 0; p < 8; ++p) {
    const int n   = (p << 5) + (t >> 3);
    const int cc8 = (t & 7) << 3;
    const unsigned short* e = &lt[n * 65 + cc8];
    uint4 pk;
    pk.x = (unsigned)e[0] | ((unsigned)e[1] << 16);
    pk.y = (unsigned)e[2] | ((unsigned)e[3] << 16);
    pk.z = (unsigned)e[4] | ((unsigned)e[5] << 16);
    pk.w = (unsigned)e[6] | ((unsigned)e[7] << 16);
    *(uint4*)(qt + ((size_t)b * NN + n0 + n) * CC + c0 + cc8) = pk;
  }
}

// ---------------- Kernel A2: sum row partials -> pooled_x raw sums --------------------
__global__ __launch_bounds__(256) void k_sumpart(const float* __restrict__ part,
                                                 float* __restrict__ px)
{
  const int g = blockIdx.x * 256 + threadIdx.x;   // 0..8191 = b*512+c
  float s = 0.f;
  #pragma unroll
  for (int i = 0; i < 16; ++i) s += part[(size_t)g * 16 + i];
  px[g] = s;
}

// ---------------- Kernel B: energy = HH + (HL+LH) (split-precision bf16 MFMA) ---------
// 128x128 tile per block, 4 waves (64x64/wave), BK=32, double-buffered gload_lds.
// KSPLIT-way K split for occupancy; XCD-grouped so one (batch,khalf)'s 16 tiles
// (which all read the SAME 4 MiB of hi+lo panels) land on one XCD's L2.
template <int KSPLIT>
__global__ __launch_bounds__(256, 2) void k_energy(
    const unsigned short* __restrict__ qhi,
    const unsigned short* __restrict__ qlo,
    float* __restrict__ EP)
{
  const int bx  = blockIdx.x;               // 256*KSPLIT blocks
  const int xcd = bx & 7;
  const int j   = bx >> 3;
  const int g   = xcd + ((j >> 4) << 3);    // group: b*KSPLIT + ks, all on one XCD
  const int t16 = j & 15;
  const int b   = g / KSPLIT;
  const int ks  = g % KSPLIT;
  const int tr  = t16 >> 2, tc = t16 & 3;
  const int kbase = ks * (NN / KSPLIT);
  const int NK    = 128 / KSPLIT;           // K-steps of 32

  const int t = threadIdx.x, w = t >> 6, l = t & 63;
  const int wr = w >> 1, wc = w & 1;

  __shared__ short lds[2][4][128 * 32];     // [buf][Ahi,Alo,Bhi,Blo]  = 64 KiB

  const size_t qoff = (size_t)b * CC * NN;
  const unsigned short* sAh = qhi + qoff + (size_t)(tr * 128) * NN;
  const unsigned short* sAl = qlo + qoff + (size_t)(tr * 128) * NN;
  const unsigned short* sBh = qhi + qoff + (size_t)(tc * 128) * NN;
  const unsigned short* sBl = qlo + qoff + (size_t)(tc * 128) * NN;

  // staging: chunk = w*64+l (and +256); row = chunk>>2; stored kchunk = chunk&3;
  // logical kchunk = stored ^ ((row>>2)&3)  (XOR swizzle, pre-swizzled source)
  const int r1 = w * 16 + (l >> 2);
  const int kl = (((l & 3) ^ (l >> 4)) << 3);          // logical k elem offset
  const int d1 = w * 512;                               // LDS short offset (wave-uniform)
  const int d2 = 2048 + w * 512;

  // fragment read: row = base + (l&15); logical chunk = l>>4; stored = logical ^ ((row>>2)&3)
  const int laneoff = ((l & 15) << 5) + ((((l >> 4) ^ ((l >> 2) & 3))) << 3);

  f32x4 acc1[4][4] = {}; f32x4 acc2[4][4] = {};

  auto stage = [&](int buf, int kk) {
    const int k0 = kbase + kk * 32 + kl;
    gload16(sAh + (size_t)r1 * NN + k0,        &lds[buf][0][d1]);
    gload16(sAh + (size_t)(r1 + 64) * NN + k0, &lds[buf][0][d2]);
    gload16(sAl + (size_t)r1 * NN + k0,        &lds[buf][1][d1]);
    gload16(sAl + (size_t)(r1 + 64) * NN + k0, &lds[buf][1][d2]);
    gload16(sBh + (size_t)r1 * NN + k0,        &lds[buf][2][d1]);
    gload16(sBh + (size_t)(r1 + 64) * NN + k0, &lds[buf][2][d2]);
    gload16(sBl + (size_t)r1 * NN + k0,        &lds[buf][3][d1]);
    gload16(sBl + (size_t)(r1 + 64) * NN + k0, &lds[buf][3][d2]);
  };

  stage(0, 0);
  __syncthreads();

  for (int kk = 0; kk < NK; ++kk) {
    const int cur = kk & 1;
    if (kk + 1 < NK) stage(cur ^ 1, kk + 1);
    const short* Ah = &lds[cur][0][0];
    const short* Al = &lds[cur][1][0];
    const short* Bh = &lds[cur][2][0];
    const short* Bl = &lds[cur][3][0];
    bf16x8 ah[4], al[4], bh[4], bl[4];
    #pragma unroll
    for (int m = 0; m < 4; ++m) {
      const int off = (wr * 64 + m * 16) * 32 + laneoff;
      ah[m] = *(const bf16x8*)(Ah + off);
      al[m] = *(const bf16x8*)(Al + off);
    }
    #pragma unroll
    for (int n = 0; n < 4; ++n) {
      const int off = (wc * 64 + n * 16) * 32 + laneoff;
      bh[n] = *(const bf16x8*)(Bh + off);
      bl[n] = *(const bf16x8*)(Bl + off);
    }
    __builtin_amdgcn_s_setprio(1);
    #pragma unroll
    for (int m = 0; m < 4; ++m)
      #pragma unroll
      for (int n = 0; n < 4; ++n) {
        acc1[m][n] = __builtin_amdgcn_mfma_f32_16x16x32_bf16(ah[m], bh[n], acc1[m][n], 0, 0, 0);
        acc2[m][n] = __builtin_amdgcn_mfma_f32_16x16x32_bf16(ah[m], bl[n], acc2[m][n], 0, 0, 0);
        acc2[m][n] = __builtin_amdgcn_mfma_f32_16x16x32_bf16(al[m], bh[n], acc2[m][n], 0, 0, 0);
      }
    __builtin_amdgcn_s_setprio(0);
    __syncthreads();
  }

  const int row0 = tr * 128 + wr * 64, col0 = tc * 128 + wc * 64;
  float* Eb = EP + (size_t)ks * BB * CC * CC + (size_t)b * CC * CC;
  #pragma unroll
  for (int m = 0; m < 4; ++m)
    #pragma unroll
    for (int n = 0; n < 4; ++n)
      #pragma unroll
      for (int r = 0; r < 4; ++r) {
        const int row = row0 + m * 16 + ((l >> 4) << 2) + r;   // C/D: row=(lane>>4)*4+reg
        const int col = col0 + n * 16 + (l & 15);              //      col=lane&15
        Eb[(size_t)row * CC + col] = acc1[m][n][r] + acc2[m][n][r];
      }
}

// ---------------- Kernel C: att = softmax(-E) per row; pooled_out = att . mean_x ------
template <int NP>
__global__ __launch_bounds__(64) void k_softmax(
    const float* __restrict__ EP, const float* __restrict__ px,
    unsigned short* __restrict__ att, float* __restrict__ po)
{
  const int bx = blockIdx.x;                  // 8192 = b*512+c
  const int b = bx >> 9, c = bx & 511;
  const int l = threadIdx.x;
  const size_t rowoff = ((size_t)b * CC + c) * CC;
  const size_t PS = (size_t)BB * CC * CC;
  float v[8];
  float mn = 1e30f;
  #pragma unroll
  for (int i = 0; i < 8; ++i) {
    float s = EP[rowoff + l + i * 64];
    #pragma unroll
    for (int p = 1; p < NP; ++p) s += EP[p * PS + rowoff + l + i * 64];
    v[i] = s; mn = fminf(mn, s);
  }
  #pragma unroll
  for (int o = 32; o > 0; o >>= 1) mn = fminf(mn, __shfl_xor(mn, o));
  float s = 0.f;
  #pragma unroll
  for (int i = 0; i < 8; ++i) { v[i] = __expf(mn - v[i]); s += v[i]; }
  float dot = 0.f;
  const float* pxb = px + (size_t)b * CC;
  #pragma unroll
  for (int i = 0; i < 8; ++i) dot += v[i] * pxb[l + i * 64];
  #pragma unroll
  for (int o = 32; o > 0; o >>= 1) { s += __shfl_xor(s, o); dot += __shfl_xor(dot, o); }
  const float inv = 1.f / s;
  unsigned short* arow = att + ((size_t)b * CC + c) * CC;
  #pragma unroll
  for (int i = 0; i < 8; ++i) arow[l + i * 64] = f2bf(v[i] * inv);
  if (l == 0) po[(size_t)b * CC + c] = dot / (s * 4096.f);
}

// ---------------- Kernel D: SE MLP -> se[b][c] -----------------------------------------
__global__ __launch_bounds__(256) void k_mlp(
    const float* __restrict__ px, const float* __restrict__ po,
    const float* __restrict__ w1, const float* __restrict__ b1,
    const float* __restrict__ w2, const float* __restrict__ b2,
    float* __restrict__ se)
{
  const int b = blockIdx.x, t = threadIdx.x;
  __shared__ float p[1024];
  __shared__ float hp[64][5];
  __shared__ float h[64];
  for (int i = t; i < 1024; i += 256)
    p[i] = (i < 512) ? px[(size_t)b * 512 + i] * (1.f / 4096.f)
                     : po[(size_t)b * 512 + i - 512];
  __syncthreads();
  {
    const int j = t >> 2, q = t & 3;
    float s = 0.f;
    const float* wr = w1 + (size_t)j * 1024 + q * 256;
    const float* pp = p + q * 256;
    for (int k = 0; k < 256; ++k) s += pp[k] * wr[k];
    hp[j][q] = s;
  }
  __syncthreads();
  if (t < 64) h[t] = fmaxf(hp[t][0] + hp[t][1] + hp[t][2] + hp[t][3] + b1[t], 0.f);
  __syncthreads();
  for (int c = t; c < 512; c += 256) {
    float s = b2[c];
    for (int j = 0; j < 64; ++j) s += h[j] * w2[(size_t)c * 64 + j];
    se[(size_t)b * 512 + c] = 1.f / (1.f + __expf(-s));
  }
}

// ---------------- Kernel E: out = att @ q, fused blend se*x + (1-se)*out --------------
__global__ __launch_bounds__(256) void k_out(
    const unsigned short* __restrict__ att,
    const unsigned short* __restrict__ qt,
    const float* __restrict__ se,
    const float* __restrict__ x,
    float* __restrict__ out)
{
  const int bx = blockIdx.x;                      // 2048 blocks, XCD-grouped per batch
  const int xcd = bx & 7;
  const int j   = bx >> 3;                        // 0..255
  const int b   = xcd + ((j >> 7) << 3);          // 0..15, one batch's 128 tiles per XCD
  const int tt  = j & 127;
  const int tr = tt >> 5, tc = tt & 31;
  const int t = threadIdx.x, w = t >> 6, l = t & 63;
  const int wr = w >> 1, wc = w & 1;

  __shared__ short lds[2][2][128 * 32];           // 32 KiB

  const unsigned short* sA = att + (size_t)b * CC * CC + (size_t)(tr * 128) * CC;
  const unsigned short* sB = qt  + (size_t)b * NN * CC + (size_t)(tc * 128) * CC;

  const int r1 = w * 16 + (l >> 2);
  const int kl = (((l & 3) ^ (l >> 4)) << 3);
  const int d1 = w * 512, d2 = 2048 + w * 512;
  const int laneoff = ((l & 15) << 5) + ((((l >> 4) ^ ((l >> 2) & 3))) << 3);

  f32x4 acc[4][4] = {};

  auto stage = [&](int buf, int kk) {
    const int k0 = kk * 32 + kl;
    gload16(sA + (size_t)r1 * CC + k0,        &lds[buf][0][d1]);
    gload16(sA + (size_t)(r1 + 64) * CC + k0, &lds[buf][0][d2]);
    gload16(sB + (size_t)r1 * CC + k0,        &lds[buf][1][d1]);
    gload16(sB + (size_t)(r1 + 64) * CC + k0, &lds[buf][1][d2]);
  };

  stage(0, 0);
  __syncthreads();

  for (int kk = 0; kk < 16; ++kk) {
    const int cur = kk & 1;
    if (kk + 1 < 16) stage(cur ^ 1, kk + 1);
    const short* A  = &lds[cur][0][0];
    const short* Bm = &lds[cur][1][0];
    bf16x8 af[4], bf[4];
    #pragma unroll
    for (int m = 0; m < 4; ++m) af[m] = *(const bf16x8*)(A  + (wr * 64 + m * 16) * 32 + laneoff);
    #pragma unroll
    for (int n = 0; n < 4; ++n) bf[n] = *(const bf16x8*)(Bm + (wc * 64 + n * 16) * 32 + laneoff);
    __builtin_amdgcn_s_setprio(1);
    #pragma unroll
    for (int m = 0; m < 4; ++m)
      #pragma unroll
      for (int n = 0; n < 4; ++n)
        acc[m][n] = __builtin_amdgcn_mfma_f32_16x16x32_bf16(af[m], bf[n], acc[m][n], 0, 0, 0);
    __builtin_amdgcn_s_setprio(0);
    __syncthreads();
  }

  const int row0 = tr * 128 + wr * 64, col0 = tc * 128 + wc * 64;
  const size_t xb = (size_t)b * CC * NN;
  #pragma unroll
  for (int m = 0; m < 4; ++m)
    #pragma unroll
    for (int r = 0; r < 4; ++r) {
      const int c = row0 + m * 16 + ((l >> 4) << 2) + r;
      const float sv = se[(size_t)b * CC + c];
      const float om = 1.f - sv;
      const size_t ro = xb + (size_t)c * NN;
      #pragma unroll
      for (int n = 0; n < 4; ++n) {
        const int ng = col0 + n * 16 + (l & 15);
        out[ro + ng] = sv * x[ro + ng] + om * acc[m][n][r];
      }
    }
}

// ---------------------------------------------------------------------------------------
extern "C" void kernel_launch(void* const* d_in, const int* in_sizes, int n_in,
                              void* d_out, int out_size, void* d_ws, size_t ws_size,
                              hipStream_t stream) {
  (void)in_sizes; (void)n_in; (void)out_size;
  const float* x  = (const float*)d_in[0];
  const float* w1 = (const float*)d_in[1];
  const float* b1 = (const float*)d_in[2];
  const float* w2 = (const float*)d_in[3];
  const float* b2 = (const float*)d_in[4];
  float* out = (float*)d_out;

  // layout offsets (bytes)
  const size_t O_QHI = 0;
  const size_t O_QLO = 67108864;
  const size_t O_QT  = 134217728;
  const size_t O_EP  = 201326592;             // KSPLIT x 16,777,216
  const size_t EPSZ1 = 16777216;

  // big path (KSPLIT=2): EP=33.5MB, then att/part/px/po/se
  const size_t B_ATT = O_EP + 2 * EPSZ1;                 // 234881024
  const size_t B_PART= B_ATT + 8388608;
  const size_t B_PX  = B_PART + 524288;
  const size_t B_PO  = B_PX + 32768;
  const size_t B_SE  = B_PO + 32768;
  const size_t NEED_BIG = B_SE + 32768;                  // 243,892,224

  // small path (KSPLIT=1): round-0 layout
  const size_t S_ATT = O_EP + EPSZ1;                     // 218103808
  const size_t S_PART= S_ATT + 8388608;
  const size_t S_PX  = S_PART + 524288;
  const size_t S_PO  = S_PX + 32768;
  const size_t S_SE  = S_PO + 32768;
  const size_t NEED_SMALL = S_SE + 32768;                // 227,115,008

  if (ws_size < NEED_SMALL) return;   // fail loudly (output stays poisoned)
  const bool big = (ws_size >= NEED_BIG);

  char* ws = (char*)d_ws;
  unsigned short* qhi = (unsigned short*)(ws + O_QHI);
  unsigned short* qlo = (unsigned short*)(ws + O_QLO);
  unsigned short* qt  = (unsigned short*)(ws + O_QT);
  float*          EP  = (float*)(ws + O_EP);
  unsigned short* att = (unsigned short*)(ws + (big ? B_ATT : S_ATT));
  float*          part= (float*)(ws + (big ? B_PART : S_PART));
  float*          px  = (float*)(ws + (big ? B_PX : S_PX));
  float*          po  = (float*)(ws + (big ? B_PO : S_PO));
  float*          se  = (float*)(ws + (big ? B_SE : S_SE));

  k_convert<<<dim3(16, 8, 16), 256, 0, stream>>>(x, qhi, qlo, qt, part);
  k_sumpart<<<32, 256, 0, stream>>>(part, px);
  if (big) {
    k_energy<2><<<512, 256, 0, stream>>>(qhi, qlo, EP);
    k_softmax<2><<<8192, 64, 0, stream>>>(EP, px, att, po);
  } else {
    k_energy<1><<<256, 256, 0, stream>>>(qhi, qlo, EP);
    k_softmax<1><<<8192, 64, 0, stream>>>(EP, px, att, po);
  }
  k_mlp<<<16, 256, 0, stream>>>(px, po, w1, b1, w2, b2, se);
  k_out<<<2048, 256, 0, stream>>>(att, qt, se, x, out);
}

// Round 3
// 312.825 us; speedup vs baseline: 1.5732x; 1.0769x over previous
//
#include <hip/hip_runtime.h>
#include <cstdint>
#include <cstddef>

#define BB 16
#define CC 512
#define NN 4096

typedef __attribute__((ext_vector_type(4))) float f32x4;
typedef __attribute__((ext_vector_type(8))) short bf16x8;

__device__ __forceinline__ unsigned short f2bf(float f) {
  unsigned int u = __float_as_uint(f);
  u += 0x7FFFu + ((u >> 16) & 1u);   // round-to-nearest-even
  return (unsigned short)(u >> 16);
}
__device__ __forceinline__ float bf2f(unsigned short h) {
  return __uint_as_float(((unsigned int)h) << 16);
}

// async global->LDS, 16B per lane. LDS dest must be wave-uniform base; HW adds lane*16.
__device__ __forceinline__ void gload16(const unsigned short* g, short* l) {
  __builtin_amdgcn_global_load_lds(
      (const __attribute__((address_space(1))) unsigned int*)g,
      (__attribute__((address_space(3))) unsigned int*)(__attribute__((address_space(3))) short*)l,
      16, 0, 0);
}

// ---------------- Kernel A: x -> bf16 hi/lo, transposed hi, row partial sums ----------
__global__ __launch_bounds__(256) void k_convert(
    const float* __restrict__ x,
    unsigned short* __restrict__ qhi,
    unsigned short* __restrict__ qlo,
    unsigned short* __restrict__ qt,
    float* __restrict__ part)
{
  const int nt = blockIdx.x;     // 16 tiles of 256 n
  const int ct = blockIdx.y;     // 8 tiles of 64 c
  const int b  = blockIdx.z;
  const int c0 = ct << 6;
  const int n0 = nt << 8;
  const int t  = threadIdx.x;
  const int w  = t >> 6;
  const int l  = t & 63;

  __shared__ unsigned short lt[256 * 65];   // [n_local][c_local], pitch 65 (bank spread)
  __shared__ float rsum[64];

  const size_t xb = (size_t)b * CC * NN;

  for (int i = 0; i < 16; ++i) {
    const int r = (i << 2) + w;                       // c row in tile (wave-uniform)
    const size_t off = xb + (size_t)(c0 + r) * NN + n0 + (l << 2);
    const float4 v = *(const float4*)(x + off);
    const unsigned short h0 = f2bf(v.x), h1 = f2bf(v.y), h2 = f2bf(v.z), h3 = f2bf(v.w);
    const unsigned short g0 = f2bf(v.x - bf2f(h0)), g1 = f2bf(v.y - bf2f(h1)),
                         g2 = f2bf(v.z - bf2f(h2)), g3 = f2bf(v.w - bf2f(h3));
    *(ushort4*)(qhi + off) = make_ushort4(h0, h1, h2, h3);
    *(ushort4*)(qlo + off) = make_ushort4(g0, g1, g2, g3);
    const int nl = l << 2;
    lt[(nl + 0) * 65 + r] = h0;
    lt[(nl + 1) * 65 + r] = h1;
    lt[(nl + 2) * 65 + r] = h2;
    lt[(nl + 3) * 65 + r] = h3;
    float s = v.x + v.y + v.z + v.w;
    #pragma unroll
    for (int o = 32; o > 0; o >>= 1) s += __shfl_down(s, o);
    if (l == 0) rsum[r] = s;                          // each wave owns distinct rows
  }
  __syncthreads();
  if (t < 64) part[((size_t)b * CC + c0 + t) * 16 + nt] = rsum[t];

  // transposed write: qt[b][n][c]
  #pragma unroll
  for (int p = 0; p < 8; ++p) {
    const int n   = (p << 5) + (t >> 3);
    const int cc8 = (t & 7) << 3;
    const unsigned short* e = &lt[n * 65 + cc8];
    uint4 pk;
    pk.x = (unsigned)e[0] | ((unsigned)e[1] << 16);
    pk.y = (unsigned)e[2] | ((unsigned)e[3] << 16);
    pk.z = (unsigned)e[4] | ((unsigned)e[5] << 16);
    pk.w = (unsigned)e[6] | ((unsigned)e[7] << 16);
    *(uint4*)(qt + ((size_t)b * NN + n0 + n) * CC + c0 + cc8) = pk;
  }
}

// ---------------- Kernel A2: sum row partials -> pooled_x raw sums --------------------
__global__ __launch_bounds__(256) void k_sumpart(const float* __restrict__ part,
                                                 float* __restrict__ px)
{
  const int g = blockIdx.x * 256 + threadIdx.x;   // 0..8191 = b*512+c
  float s = 0.f;
  #pragma unroll
  for (int i = 0; i < 16; ++i) s += part[(size_t)g * 16 + i];
  px[g] = s;
}

// ---------------- Kernel B: energy = HH + (HL+LH), SYMMETRIC upper-tri only ----------
// 128x128 tile, 4 waves, BK=32, double-buffered gload_lds. Only tr<=tc tiles are
// computed (10 of 16); off-diag results are mirror-written. Diagonal aliases B:=A.
template <int KSPLIT>
__global__ __launch_bounds__(256, 2) void k_energy(
    const unsigned short* __restrict__ qhi,
    const unsigned short* __restrict__ qlo,
    float* __restrict__ EP)
{
  const int bx  = blockIdx.x;               // 160*KSPLIT blocks
  const int xcd = bx & 7;
  const int j   = bx >> 3;
  const int gi  = j / 10;
  const int t10 = j % 10;
  const int g   = xcd + (gi << 3);          // group = b*KSPLIT+ks, grouped per XCD
  const int b   = g / KSPLIT;
  const int ks  = g % KSPLIT;
  int tr, tc;
  if (t10 < 4)      { tr = 0; tc = t10; }
  else if (t10 < 7) { tr = 1; tc = t10 - 3; }
  else if (t10 < 9) { tr = 2; tc = t10 - 5; }
  else              { tr = 3; tc = 3; }
  const bool diag = (tr == tc);
  const int kbase = ks * (NN / KSPLIT);
  const int NK    = 128 / KSPLIT;           // K-steps of 32

  const int t = threadIdx.x, w = t >> 6, l = t & 63;
  const int wr = w >> 1, wc = w & 1;

  __shared__ short lds[2][4][128 * 32];     // [buf][Ahi,Alo,Bhi,Blo]  = 64 KiB

  const size_t qoff = (size_t)b * CC * NN;
  const unsigned short* sAh = qhi + qoff + (size_t)(tr * 128) * NN;
  const unsigned short* sAl = qlo + qoff + (size_t)(tr * 128) * NN;
  const unsigned short* sBh = qhi + qoff + (size_t)(tc * 128) * NN;
  const unsigned short* sBl = qlo + qoff + (size_t)(tc * 128) * NN;

  // staging: chunk = w*64+l; row = chunk>>2; stored kchunk = chunk&3;
  // logical kchunk = stored ^ ((row>>2)&3)  (XOR swizzle, pre-swizzled source)
  const int r1 = w * 16 + (l >> 2);
  const int kl = (((l & 3) ^ (l >> 4)) << 3);          // logical k elem offset
  const int d1 = w * 512;                               // LDS short offset (wave-uniform)
  const int d2 = 2048 + w * 512;

  // fragment read: row = base + (l&15); logical chunk = l>>4; stored = logical ^ ((row>>2)&3)
  const int laneoff = ((l & 15) << 5) + ((((l >> 4) ^ ((l >> 2) & 3))) << 3);

  f32x4 acc1[4][4] = {}; f32x4 acc2[4][4] = {};

  auto stage = [&](int buf, int kk) {
    const int k0 = kbase + kk * 32 + kl;
    gload16(sAh + (size_t)r1 * NN + k0,        &lds[buf][0][d1]);
    gload16(sAh + (size_t)(r1 + 64) * NN + k0, &lds[buf][0][d2]);
    gload16(sAl + (size_t)r1 * NN + k0,        &lds[buf][1][d1]);
    gload16(sAl + (size_t)(r1 + 64) * NN + k0, &lds[buf][1][d2]);
    if (!diag) {
      gload16(sBh + (size_t)r1 * NN + k0,        &lds[buf][2][d1]);
      gload16(sBh + (size_t)(r1 + 64) * NN + k0, &lds[buf][2][d2]);
      gload16(sBl + (size_t)r1 * NN + k0,        &lds[buf][3][d1]);
      gload16(sBl + (size_t)(r1 + 64) * NN + k0, &lds[buf][3][d2]);
    }
  };

  stage(0, 0);
  __syncthreads();

  for (int kk = 0; kk < NK; ++kk) {
    const int cur = kk & 1;
    if (kk + 1 < NK) stage(cur ^ 1, kk + 1);
    const short* Ah = &lds[cur][0][0];
    const short* Al = &lds[cur][1][0];
    const short* Bh = diag ? Ah : &lds[cur][2][0];
    const short* Bl = diag ? Al : &lds[cur][3][0];
    bf16x8 ah[4], al[4], bh[4], bl[4];
    #pragma unroll
    for (int m = 0; m < 4; ++m) {
      const int off = (wr * 64 + m * 16) * 32 + laneoff;
      ah[m] = *(const bf16x8*)(Ah + off);
      al[m] = *(const bf16x8*)(Al + off);
    }
    #pragma unroll
    for (int n = 0; n < 4; ++n) {
      const int off = (wc * 64 + n * 16) * 32 + laneoff;
      bh[n] = *(const bf16x8*)(Bh + off);
      bl[n] = *(const bf16x8*)(Bl + off);
    }
    __builtin_amdgcn_s_setprio(1);
    #pragma unroll
    for (int m = 0; m < 4; ++m)
      #pragma unroll
      for (int n = 0; n < 4; ++n) {
        acc1[m][n] = __builtin_amdgcn_mfma_f32_16x16x32_bf16(ah[m], bh[n], acc1[m][n], 0, 0, 0);
        acc2[m][n] = __builtin_amdgcn_mfma_f32_16x16x32_bf16(ah[m], bl[n], acc2[m][n], 0, 0, 0);
        acc2[m][n] = __builtin_amdgcn_mfma_f32_16x16x32_bf16(al[m], bh[n], acc2[m][n], 0, 0, 0);
      }
    __builtin_amdgcn_s_setprio(0);
    __syncthreads();
  }

  const int row0 = tr * 128 + wr * 64, col0 = tc * 128 + wc * 64;
  float* Eb = EP + ((size_t)ks * BB + b) * CC * CC;
  #pragma unroll
  for (int m = 0; m < 4; ++m)
    #pragma unroll
    for (int n = 0; n < 4; ++n)
      #pragma unroll
      for (int r = 0; r < 4; ++r) {
        const int row = row0 + m * 16 + ((l >> 4) << 2) + r;   // C/D: row=(lane>>4)*4+reg
        const int col = col0 + n * 16 + (l & 15);              //      col=lane&15
        const float v = acc1[m][n][r] + acc2[m][n][r];
        Eb[(size_t)row * CC + col] = v;
        if (!diag) Eb[(size_t)col * CC + row] = v;   // mirror (L2 merges the scatter)
      }
}

// ---------------- Kernel C: att = softmax(-E) per row; pooled_out = att . mean_x ------
template <int NP>
__global__ __launch_bounds__(64) void k_softmax(
    const float* __restrict__ EP, const float* __restrict__ px,
    unsigned short* __restrict__ att, float* __restrict__ po)
{
  const int bx = blockIdx.x;                  // 8192 = b*512+c
  const int b = bx >> 9, c = bx & 511;
  const int l = threadIdx.x;
  const size_t rowoff = ((size_t)b * CC + c) * CC;
  const size_t PS = (size_t)BB * CC * CC;
  float v[8];
  float mn = 1e30f;
  #pragma unroll
  for (int i = 0; i < 8; ++i) {
    float s = EP[rowoff + l + i * 64];
    #pragma unroll
    for (int p = 1; p < NP; ++p) s += EP[p * PS + rowoff + l + i * 64];
    v[i] = s; mn = fminf(mn, s);
  }
  #pragma unroll
  for (int o = 32; o > 0; o >>= 1) mn = fminf(mn, __shfl_xor(mn, o));
  float s = 0.f;
  #pragma unroll
  for (int i = 0; i < 8; ++i) { v[i] = __expf(mn - v[i]); s += v[i]; }
  float dot = 0.f;
  const float* pxb = px + (size_t)b * CC;
  #pragma unroll
  for (int i = 0; i < 8; ++i) dot += v[i] * pxb[l + i * 64];
  #pragma unroll
  for (int o = 32; o > 0; o >>= 1) { s += __shfl_xor(s, o); dot += __shfl_xor(dot, o); }
  const float inv = 1.f / s;
  unsigned short* arow = att + ((size_t)b * CC + c) * CC;
  #pragma unroll
  for (int i = 0; i < 8; ++i) arow[l + i * 64] = f2bf(v[i] * inv);
  if (l == 0) po[(size_t)b * CC + c] = dot / (s * 4096.f);
}

// ---------------- Kernel D: SE MLP -> se[b][c] -----------------------------------------
__global__ __launch_bounds__(256) void k_mlp(
    const float* __restrict__ px, const float* __restrict__ po,
    const float* __restrict__ w1, const float* __restrict__ b1,
    const float* __restrict__ w2, const float* __restrict__ b2,
    float* __restrict__ se)
{
  const int b = blockIdx.x, t = threadIdx.x;
  __shared__ float p[1024];
  __shared__ float hp[64][5];
  __shared__ float h[64];
  for (int i = t; i < 1024; i += 256)
    p[i] = (i < 512) ? px[(size_t)b * 512 + i] * (1.f / 4096.f)
                     : po[(size_t)b * 512 + i - 512];
  __syncthreads();
  {
    const int j = t >> 2, q = t & 3;
    float s = 0.f;
    const float* wr = w1 + (size_t)j * 1024 + q * 256;
    const float* pp = p + q * 256;
    for (int k = 0; k < 256; ++k) s += pp[k] * wr[k];
    hp[j][q] = s;
  }
  __syncthreads();
  if (t < 64) h[t] = fmaxf(hp[t][0] + hp[t][1] + hp[t][2] + hp[t][3] + b1[t], 0.f);
  __syncthreads();
  for (int c = t; c < 512; c += 256) {
    float s = b2[c];
    for (int j = 0; j < 64; ++j) s += h[j] * w2[(size_t)c * 64 + j];
    se[(size_t)b * 512 + c] = 1.f / (1.f + __expf(-s));
  }
}

// ---------------- Kernel E: out = att @ q, fused blend se*x + (1-se)*out --------------
// Blend reads qhi (bf16 of x; same layout) -> halves x traffic. Epilogue stages each
// wave's quadrant through a private LDS slab for float4-coalesced global IO.
__global__ __launch_bounds__(256) void k_out(
    const unsigned short* __restrict__ att,
    const unsigned short* __restrict__ qt,
    const float* __restrict__ se,
    const unsigned short* __restrict__ qhi,
    float* __restrict__ out)
{
  const int bx = blockIdx.x;                      // 2048 blocks, XCD-grouped per batch
  const int xcd = bx & 7;
  const int j   = bx >> 3;                        // 0..255
  const int b   = xcd + ((j >> 7) << 3);          // 0..15, one batch's 128 tiles per XCD
  const int tt  = j & 127;
  const int tr = tt >> 5, tc = tt & 31;
  const int t = threadIdx.x, w = t >> 6, l = t & 63;
  const int wr = w >> 1, wc = w & 1;

  __shared__ short lds[2][2][128 * 32];           // 32 KiB (reused as epilogue slabs)

  const unsigned short* sA = att + (size_t)b * CC * CC + (size_t)(tr * 128) * CC;
  const unsigned short* sB = qt  + (size_t)b * NN * CC + (size_t)(tc * 128) * CC;

  const int r1 = w * 16 + (l >> 2);
  const int kl = (((l & 3) ^ (l >> 4)) << 3);
  const int d1 = w * 512, d2 = 2048 + w * 512;
  const int laneoff = ((l & 15) << 5) + ((((l >> 4) ^ ((l >> 2) & 3))) << 3);

  f32x4 acc[4][4] = {};

  auto stage = [&](int buf, int kk) {
    const int k0 = kk * 32 + kl;
    gload16(sA + (size_t)r1 * CC + k0,        &lds[buf][0][d1]);
    gload16(sA + (size_t)(r1 + 64) * CC + k0, &lds[buf][0][d2]);
    gload16(sB + (size_t)r1 * CC + k0,        &lds[buf][1][d1]);
    gload16(sB + (size_t)(r1 + 64) * CC + k0, &lds[buf][1][d2]);
  };

  stage(0, 0);
  __syncthreads();

  for (int kk = 0; kk < 16; ++kk) {
    const int cur = kk & 1;
    if (kk + 1 < 16) stage(cur ^ 1, kk + 1);
    const short* A  = &lds[cur][0][0];
    const short* Bm = &lds[cur][1][0];
    bf16x8 af[4], bf[4];
    #pragma unroll
    for (int m = 0; m < 4; ++m) af[m] = *(const bf16x8*)(A  + (wr * 64 + m * 16) * 32 + laneoff);
    #pragma unroll
    for (int n = 0; n < 4; ++n) bf[n] = *(const bf16x8*)(Bm + (wc * 64 + n * 16) * 32 + laneoff);
    __builtin_amdgcn_s_setprio(1);
    #pragma unroll
    for (int m = 0; m < 4; ++m)
      #pragma unroll
      for (int n = 0; n < 4; ++n)
        acc[m][n] = __builtin_amdgcn_mfma_f32_16x16x32_bf16(af[m], bf[n], acc[m][n], 0, 0, 0);
    __builtin_amdgcn_s_setprio(0);
    __syncthreads();
  }

  // ---- epilogue: per-wave LDS slab (16 rows x 68 pitch), float4-coalesced IO ----
  float* slab = (float*)(&lds[0][0][0]) + w * (16 * 68);   // 4*16*68*4B = 17408B total
  const int row0 = tr * 128 + wr * 64, col0q = tc * 128 + wc * 64;
  const size_t xb = (size_t)b * CC * NN;
  const float* seb = se + (size_t)b * CC;
  #pragma unroll
  for (int m = 0; m < 4; ++m) {
    #pragma unroll
    for (int n = 0; n < 4; ++n)
      #pragma unroll
      for (int r = 0; r < 4; ++r)
        slab[(((l >> 4) << 2) + r) * 68 + n * 16 + (l & 15)] = acc[m][n][r];
    #pragma unroll
    for (int it = 0; it < 4; ++it) {
      const int rl = (it << 2) + (l >> 4);
      const int c  = row0 + m * 16 + rl;
      const int n4 = (l & 15) << 2;
      const float4 a = *(const float4*)&slab[rl * 68 + n4];
      const float sv = seb[c];
      const float om = 1.f - sv;
      const size_t go = xb + (size_t)c * NN + col0q + n4;
      const ushort4 hx = *(const ushort4*)(qhi + go);
      float4 o;
      o.x = sv * bf2f(hx.x) + om * a.x;
      o.y = sv * bf2f(hx.y) + om * a.y;
      o.z = sv * bf2f(hx.z) + om * a.z;
      o.w = sv * bf2f(hx.w) + om * a.w;
      *(float4*)(out + go) = o;
    }
  }
}

// ---------------------------------------------------------------------------------------
extern "C" void kernel_launch(void* const* d_in, const int* in_sizes, int n_in,
                              void* d_out, int out_size, void* d_ws, size_t ws_size,
                              hipStream_t stream) {
  (void)in_sizes; (void)n_in; (void)out_size;
  const float* x  = (const float*)d_in[0];
  const float* w1 = (const float*)d_in[1];
  const float* b1 = (const float*)d_in[2];
  const float* w2 = (const float*)d_in[3];
  const float* b2 = (const float*)d_in[4];
  float* out = (float*)d_out;

  const size_t O_QHI = 0;
  const size_t O_QLO = 67108864;
  const size_t O_QT  = 134217728;
  const size_t O_EP  = 201326592;
  const size_t EPSZ1 = 16777216;

  // need(KS) = O_EP + KS*EPSZ1 + att(8388608) + part(524288) + px/po/se(3*32768)
  const size_t TAIL = 8388608 + 524288 + 3 * 32768;      // 9,011,200
  const size_t NEED1 = O_EP + 1 * EPSZ1 + TAIL;          // 227,115,008
  const size_t NEED2 = O_EP + 2 * EPSZ1 + TAIL;          // 243,892,224
  const size_t NEED4 = O_EP + 4 * EPSZ1 + TAIL;          // 277,446,656

  if (ws_size < NEED1) return;   // fail loudly (output stays poisoned)
  const int ksplit = (ws_size >= NEED4) ? 4 : (ws_size >= NEED2) ? 2 : 1;

  char* ws = (char*)d_ws;
  unsigned short* qhi = (unsigned short*)(ws + O_QHI);
  unsigned short* qlo = (unsigned short*)(ws + O_QLO);
  unsigned short* qt  = (unsigned short*)(ws + O_QT);
  float*          EP  = (float*)(ws + O_EP);
  char* tail          = ws + O_EP + (size_t)ksplit * EPSZ1;
  unsigned short* att = (unsigned short*)(tail);
  float*          part= (float*)(tail + 8388608);
  float*          px  = (float*)(tail + 8912896);
  float*          po  = (float*)(tail + 8945664);
  float*          se  = (float*)(tail + 8978432);

  k_convert<<<dim3(16, 8, 16), 256, 0, stream>>>(x, qhi, qlo, qt, part);
  k_sumpart<<<32, 256, 0, stream>>>(part, px);
  if (ksplit == 4) {
    k_energy<4><<<640, 256, 0, stream>>>(qhi, qlo, EP);
    k_softmax<4><<<8192, 64, 0, stream>>>(EP, px, att, po);
  } else if (ksplit == 2) {
    k_energy<2><<<320, 256, 0, stream>>>(qhi, qlo, EP);
    k_softmax<2><<<8192, 64, 0, stream>>>(EP, px, att, po);
  } else {
    k_energy<1><<<160, 256, 0, stream>>>(qhi, qlo, EP);
    k_softmax<1><<<8192, 64, 0, stream>>>(EP, px, att, po);
  }
  k_mlp<<<16, 256, 0, stream>>>(px, po, w1, b1, w2, b2, se);
  k_out<<<2048, 256, 0, stream>>>(att, qt, se, qhi, out);
}